// Round 10
// baseline (518.540 us; speedup 1.0000x reference)
//
#include <hip/hip_runtime.h>
#include <hip/hip_bf16.h>

typedef __hip_bfloat16 bf16;
typedef __attribute__((ext_vector_type(4))) float f32x4;
typedef __attribute__((ext_vector_type(8))) short bf16x8v;

static constexpr int   HD    = 768;
static constexpr int   NRr   = 8192;     // B*T
static constexpr int   SSAMP = 256;
static constexpr int   KTOP  = 64;
static constexpr int   NPOOL = 1024;
static constexpr float TINV  = 10.0f;    // 1/TEMP

__device__ __forceinline__ float bf2f(bf16 h){ return __bfloat162float(h); }
__device__ __forceinline__ bf16  f2bf(float f){ return __float2bfloat16(f); }

__device__ __forceinline__ float gelu_exact(float x){
  return 0.5f * x * (1.0f + erff(x * 0.70710678118654752f));
}

// deterministic block sum; buf must hold blockDim.x/64 floats
__device__ __forceinline__ float block_sum(float v, float* buf){
  const int lane = threadIdx.x & 63, w = threadIdx.x >> 6;
  const int nw = (int)blockDim.x >> 6;
  #pragma unroll
  for(int o = 32; o; o >>= 1) v += __shfl_down(v, o);
  __syncthreads();
  if(lane == 0) buf[w] = v;
  __syncthreads();
  float t = 0.f;
  for(int i = 0; i < nw; i++) t += buf[i];
  return t;
}

// dual block sum (256 threads); buf must hold 8 floats
__device__ __forceinline__ void block_sum2(float& a, float& b, float* buf){
  const int lane = threadIdx.x & 63, w = threadIdx.x >> 6;
  #pragma unroll
  for(int o = 32; o; o >>= 1){ a += __shfl_down(a, o); b += __shfl_down(b, o); }
  __syncthreads();
  if(lane == 0){ buf[w] = a; buf[4 + w] = b; }
  __syncthreads();
  float ta = 0.f, tb = 0.f;
  #pragma unroll
  for(int i = 0; i < 4; i++){ ta += buf[i]; tb += buf[4 + i]; }
  a = ta; b = tb;
}

__device__ __forceinline__ void gload_lds16(const bf16* g, bf16* lds_uniform){
  __builtin_amdgcn_global_load_lds(
      (const __attribute__((address_space(1))) unsigned int*)(const void*)g,
      (__attribute__((address_space(3))) unsigned int*)(void*)lds_uniform,
      16, 0, 0);
}

// ---- fused 6x transpose 768x768 with optional gain fold ---------------------
struct TsA { const float* w[6]; const float* gg[6]; bf16* o[6]; };
__global__ __launch_bounds__(256)
void tscale6(TsA a){
  __shared__ float t[32][33];
  const int z = blockIdx.z;
  const float* Win = a.w[z];
  const float* g   = a.gg[z];
  bf16* Wt         = a.o[z];
  const int tx = threadIdx.x, ty = threadIdx.y;     // (32,8)
  const int bx = blockIdx.x * 32, by = blockIdx.y * 32;
  #pragma unroll
  for(int j = 0; j < 4; j++)
    t[ty + j*8][tx] = Win[(size_t)(by + ty + j*8) * HD + bx + tx];
  __syncthreads();
  const float gv = g ? g[by + tx] : 1.0f;
  #pragma unroll
  for(int j = 0; j < 4; j++)
    Wt[(size_t)(bx + ty + j*8) * HD + by + tx] = f2bf(gv * t[tx][ty + j*8]);
}

// ---- fused folded-bias: o[h][n] = b1[h][n] + sum_k bln[h][k]*w1[h][k][n] ----
struct FbA { const float* bln[3]; const float* w1[3]; const float* b1[3]; float* o[3]; };
__global__ __launch_bounds__(256)
void foldbias3(FbA a){
  __shared__ float red[4][64];
  const int h = blockIdx.y;
  const int lane = threadIdx.x & 63, w = threadIdx.x >> 6;
  const int n = blockIdx.x * 64 + lane;
  const float* bl = a.bln[h];
  const float* w1 = a.w1[h];
  float t = 0.f;
  for(int k = w * 192; k < w * 192 + 192; k++)
    t += bl[k] * w1[(size_t)k * HD + n];
  red[w][lane] = t;
  __syncthreads();
  if(w == 0)
    a.o[h][n] = a.b1[h][n] + red[0][lane] + red[1][lane] + red[2][lane] + red[3][lane];
}

// ---- LayerNorm core xh=(x-m)/sigma (affine folded into weights), f32->bf16 --
__global__ __launch_bounds__(256)
void lnxh_kernel(const float* __restrict__ x, bf16* __restrict__ o){
  __shared__ float buf[4];
  const int row = blockIdx.x, tid = threadIdx.x;
  const size_t base = (size_t)row * HD;
  float v[3];
  #pragma unroll
  for(int j = 0; j < 3; j++) v[j] = x[base + tid + j*256];
  float s = v[0] + v[1] + v[2];
  s = block_sum(s, buf);
  const float m = s * (1.0f / HD);
  float q = 0.f;
  #pragma unroll
  for(int j = 0; j < 3; j++){ const float d = v[j] - m; q += d*d; }
  q = block_sum(q, buf);
  const float inv = rsqrtf(q * (1.0f / HD) + 1e-5f);
  #pragma unroll
  for(int j = 0; j < 3; j++)
    o[base + tid + j*256] = f2bf((v[j] - m) * inv);
}

// ---- fused: aligned = sc*latent+bi (write f32) + dual noisy LN -> X (bf16) --
__global__ __launch_bounds__(256)
void fuse_al_ln(const float* __restrict__ latent, const float* __restrict__ sc,
                const float* __restrict__ bi, const float* __restrict__ na,
                const float* __restrict__ nb, float* __restrict__ out_aligned,
                bf16* __restrict__ X){
  __shared__ float buf[8];
  const int row = blockIdx.x, tid = threadIdx.x;
  const size_t base = (size_t)row * HD;
  float ua[3], ub[3];
  #pragma unroll
  for(int j = 0; j < 3; j++){
    const int i = tid + j*256;
    const float a = sc[base + i] * latent[base + i] + bi[base + i];
    out_aligned[base + i] = a;
    ua[j] = a + na[base + i];
    ub[j] = a + nb[base + i];
  }
  float sa = ua[0] + ua[1] + ua[2];
  float sb = ub[0] + ub[1] + ub[2];
  block_sum2(sa, sb, buf);
  const float ma = sa * (1.0f / HD), mb = sb * (1.0f / HD);
  float qa = 0.f, qb = 0.f;
  #pragma unroll
  for(int j = 0; j < 3; j++){
    const float da = ua[j] - ma; qa += da*da;
    const float db = ub[j] - mb; qb += db*db;
  }
  block_sum2(qa, qb, buf);
  const float ia = rsqrtf(qa * (1.0f / HD) + 1e-5f);
  const float ib = rsqrtf(qb * (1.0f / HD) + 1e-5f);
  #pragma unroll
  for(int j = 0; j < 3; j++){
    const int i = tid + j*256;
    X[base + i] = f2bf((ua[j] - ma) * ia);
    X[(size_t)(row + NRr) * HD + i] = f2bf((ub[j] - mb) * ib);
  }
}

// ---------------- GEMM: C[M,N] = A[M,K] * Bt[N,K]^T, BK=64, fused epilogues --
// LDS granule swizzle (8 granules/row): phys p of row r holds global granule
// g=(p-(r&7))&7; reader of logical granule gl uses p=((gl)+(r16&7))&7.
enum { EPI_GELU = 0, EPI_SB = 1, EPI_RAW = 3, EPI_LOGITS = 4 };

template<int EPI>
__global__ __launch_bounds__(256, 2)
void gemm_kernel(const bf16* __restrict__ A, const bf16* __restrict__ Bt,
                 const bf16* __restrict__ Bt2,
                 const int M, const int N, const int K,
                 const int lda, const int ldc,
                 const float* __restrict__ bias, const float* __restrict__ bias2,
                 bf16* __restrict__ outb, float* __restrict__ outf,
                 float* __restrict__ outf2,
                 float* __restrict__ aux, float* __restrict__ aux2){
  __shared__ __align__(16) bf16 As[128 * 64];
  __shared__ __align__(16) bf16 Bs[128 * 64];
  __shared__ float rbuf[512];

  const int tid  = threadIdx.x;
  const int wave = tid >> 6, lane = tid & 63;
  const int wm = wave >> 1, wn = wave & 1;
  const int r16 = lane & 15, kh = lane >> 4;
  const int bx = blockIdx.x, by = blockIdx.y;
  const int row0 = by * 128, col0 = bx * 128;

  float addv = 0.f;
  if constexpr(EPI == EPI_SB){
    if(blockIdx.z == 0){ addv = 1.0f; }
    else { A += 768; Bt = Bt2; bias = bias2; outf = outf2; }
  }

  f32x4 acc[4][4];
  #pragma unroll
  for(int i = 0; i < 4; i++)
    #pragma unroll
    for(int j = 0; j < 4; j++){ f32x4 z = {0.f,0.f,0.f,0.f}; acc[i][j] = z; }

  // staging: tile 128x64 bf16 = 1024 chunks of 16B; chunk c: row=c>>3, p=c&7
  const bf16* gA[4]; const bf16* gB[4];
  bf16* lA[4]; bf16* lB[4];
  #pragma unroll
  for(int j = 0; j < 4; j++){
    const int c = tid + j*256;
    const int rr = c >> 3, p = c & 7;
    const int g = (p - (rr & 7)) & 7;           // pre-swizzled global granule
    gA[j] = A  + (size_t)(row0 + rr) * lda + g * 8;
    gB[j] = Bt + (size_t)(col0 + rr) * K   + g * 8;
    lA[j] = As + ((size_t)j*256 + wave*64) * 8; // wave-uniform LDS bases (linear)
    lB[j] = Bs + ((size_t)j*256 + wave*64) * 8;
  }
  const int sw = r16 & 7;

  for(int k0 = 0; k0 < K; k0 += 64){
    __syncthreads();
    #pragma unroll
    for(int j = 0; j < 4; j++){
      gload_lds16(gA[j] + k0, lA[j]);
      gload_lds16(gB[j] + k0, lB[j]);
    }
    __syncthreads();
    #pragma unroll
    for(int kk = 0; kk < 2; kk++){
      const int koff = ((kk*4 + kh + sw) & 7) * 8;
      bf16x8v av[4], bv[4];
      #pragma unroll
      for(int f = 0; f < 4; f++){
        av[f] = *(const bf16x8v*)(As + (wm*64 + f*16 + r16) * 64 + koff);
        bv[f] = *(const bf16x8v*)(Bs + (wn*64 + f*16 + r16) * 64 + koff);
      }
      #pragma unroll
      for(int i = 0; i < 4; i++)
        #pragma unroll
        for(int j = 0; j < 4; j++)
          acc[i][j] = __builtin_amdgcn_mfma_f32_16x16x32_bf16(av[i], bv[j], acc[i][j], 0, 0, 0);
    }
  }

  const int crow0 = row0 + wm * 64;
  const int ccol0 = col0 + wn * 64;

  if constexpr(EPI != EPI_LOGITS){
    float part = 0.f;
    #pragma unroll
    for(int i = 0; i < 4; i++){
      #pragma unroll
      for(int j = 0; j < 4; j++){
        const int col = ccol0 + j*16 + r16;
        const float bvv = bias ? bias[col] : 0.f;
        #pragma unroll
        for(int q = 0; q < 4; q++){
          const int row = crow0 + i*16 + kh*4 + q;
          const float v = acc[i][j][q] + bvv;
          const size_t off = (size_t)row * ldc + col;
          if constexpr(EPI == EPI_GELU){
            outb[off] = f2bf(gelu_exact(v));
          } else if constexpr(EPI == EPI_SB){
            const float t = 0.25f * tanhf(v);
            outf[off] = t + addv;
            part += t * t;
          } else {                      // EPI_RAW: bf16 out, l2norm later
            outb[off] = f2bf(v);
          }
        }
      }
    }
    if constexpr(EPI == EPI_SB){
      const float tot2 = block_sum(part, rbuf);
      if(tid == 0)
        aux[(size_t)blockIdx.z * (gridDim.x * gridDim.y) + by * gridDim.x + bx] = tot2;
    }
  } else {
    // logits tile: e = exp(10*acc); deterministic row/col partial sums
    float rs[16], cs[4];
    #pragma unroll
    for(int t = 0; t < 16; t++) rs[t] = 0.f;
    #pragma unroll
    for(int t = 0; t < 4; t++) cs[t] = 0.f;
    #pragma unroll
    for(int i = 0; i < 4; i++)
      #pragma unroll
      for(int j = 0; j < 4; j++)
        #pragma unroll
        for(int q = 0; q < 4; q++){
          const float ev = expf(acc[i][j][q] * TINV);
          rs[i*4 + q] += ev;
          cs[j]       += ev;
        }
    #pragma unroll
    for(int t = 0; t < 16; t++){
      float r = rs[t];
      r += __shfl_xor(r, 1); r += __shfl_xor(r, 2);
      r += __shfl_xor(r, 4); r += __shfl_xor(r, 8);
      rs[t] = r;
    }
    if(r16 == 0){
      #pragma unroll
      for(int i = 0; i < 4; i++)
        #pragma unroll
        for(int q = 0; q < 4; q++)
          rbuf[wn*128 + wm*64 + i*16 + kh*4 + q] = rs[i*4 + q];
    }
    #pragma unroll
    for(int j = 0; j < 4; j++){
      float c = cs[j];
      c += __shfl_xor(c, 16); c += __shfl_xor(c, 32);
      cs[j] = c;
    }
    if(kh == 0){
      #pragma unroll
      for(int j = 0; j < 4; j++)
        rbuf[256 + wm*128 + wn*64 + j*16 + r16] = cs[j];
    }
    __syncthreads();
    if(tid < 128){
      aux [(size_t)bx * M + row0 + tid] = rbuf[tid]       + rbuf[128 + tid];
      aux2[(size_t)by * M + col0 + tid] = rbuf[256 + tid] + rbuf[384 + tid];
    }
  }
}

// ---- fused: in-place l2-normalize va & vb row + diag = 10*dot(van, vbn) -----
// Numerics match r9: diag dot uses the bf16-rounded normalized values.
__global__ __launch_bounds__(256)
void l2ndiag_kernel(bf16* __restrict__ vab, float* __restrict__ diag){
  __shared__ float buf[8];
  const int row = blockIdx.x, tid = threadIdx.x;
  const size_t basea = (size_t)row * HD;
  const size_t baseb = basea + (size_t)NRr * HD;
  float a[3], b[3];
  #pragma unroll
  for(int j = 0; j < 3; j++){
    a[j] = bf2f(vab[basea + tid + j*256]);
    b[j] = bf2f(vab[baseb + tid + j*256]);
  }
  float qa = a[0]*a[0] + a[1]*a[1] + a[2]*a[2];
  float qb = b[0]*b[0] + b[1]*b[1] + b[2]*b[2];
  block_sum2(qa, qb, buf);
  const float ia = 1.0f / fmaxf(sqrtf(qa), 1e-12f);
  const float ib = 1.0f / fmaxf(sqrtf(qb), 1e-12f);
  float d = 0.f;
  #pragma unroll
  for(int j = 0; j < 3; j++){
    const bf16 oa = f2bf(a[j] * ia);
    const bf16 ob = f2bf(b[j] * ib);
    vab[basea + tid + j*256] = oa;
    vab[baseb + tid + j*256] = ob;
    d += bf2f(oa) * bf2f(ob);
  }
  d = block_sum(d, buf);
  if(tid == 0) diag[row] = d * TINV;
}

// ---------------- sum partials per row/col -----------------------------------
__global__ __launch_bounds__(256)
void rcsum_kernel(const float* __restrict__ rp, const float* __restrict__ cp,
                  float* __restrict__ rs, float* __restrict__ cs, const int nb){
  const int i = blockIdx.x * 256 + threadIdx.x;
  float r = 0.f, c = 0.f;
  for(int b = 0; b < nb; b++){
    r += rp[(size_t)b * NRr + i];
    c += cp[(size_t)b * NRr + i];
  }
  rs[i] = r; cs[i] = c;
}

// ------- fused gather: af rows (blocks 0..255) + te rows (256..1279) ---------
__global__ __launch_bounds__(256)
void gather_kernel(const float* __restrict__ aligned, const int* __restrict__ samp,
                   float* __restrict__ afraw, bf16* __restrict__ afn,
                   const float* __restrict__ emb, const int* __restrict__ tok,
                   float* __restrict__ teg, bf16* __restrict__ ten){
  __shared__ float buf[4];
  const int tid = threadIdx.x;
  if(blockIdx.x < SSAMP){
    const int s = blockIdx.x;
    const size_t src = (size_t)samp[s] * HD, dst = (size_t)s * HD;
    float v[3];
    #pragma unroll
    for(int j = 0; j < 3; j++){
      const int i = tid + j*256;
      v[j] = aligned[src + i];
      afraw[dst + i] = v[j];
    }
    float q = v[0]*v[0] + v[1]*v[1] + v[2]*v[2];
    q = block_sum(q, buf);
    const float inv = 1.0f / fmaxf(sqrtf(q), 1e-12f);
    #pragma unroll
    for(int j = 0; j < 3; j++) afn[dst + tid + j*256] = f2bf(v[j] * inv);
  } else {
    const int p = blockIdx.x - SSAMP;
    const size_t src = (size_t)tok[p] * HD, dst = (size_t)p * HD;
    float v[3];
    #pragma unroll
    for(int j = 0; j < 3; j++){
      const int i = tid + j*256;
      v[j] = emb[src + i];
      teg[dst + i] = v[j];
    }
    float q = v[0]*v[0] + v[1]*v[1] + v[2]*v[2];
    q = block_sum(q, buf);
    const float inv = 1.0f / fmaxf(sqrtf(q), 1e-12f);
    #pragma unroll
    for(int j = 0; j < 3; j++) ten[dst + tid + j*256] = f2bf(v[j] * inv);
  }
}

// ---- per-row: sims (inline tl) -> top-64 -> softmax -> proto -> sq-err ------
__global__ __launch_bounds__(256)
void topk_kernel(const bf16* __restrict__ afn, const bf16* __restrict__ ten,
                 const float* __restrict__ teg, const float* __restrict__ afraw,
                 float* __restrict__ protopart){
  __shared__ float saf[HD];
  __shared__ float sv[NPOOL];
  __shared__ float topv[KTOP];
  __shared__ int   topi[KTOP];
  __shared__ float wts[KTOP];
  __shared__ float rv[4];
  __shared__ int   ri[4];
  __shared__ float buf[4];
  __shared__ float sinv;
  const int s = blockIdx.x, tid = threadIdx.x;
  const int lane = tid & 63, w = tid >> 6;
  // load normalized af row into LDS (f32)
  #pragma unroll
  for(int j = 0; j < 3; j++) saf[tid + j*256] = bf2f(afn[(size_t)s * HD + tid + j*256]);
  __syncthreads();
  // inline tl: sv[c] = 10 * dot(afn[s], ten[c])
  #pragma unroll
  for(int cb = 0; cb < 4; cb++){
    const int c = tid + cb * 256;
    const bf16* tr = ten + (size_t)c * HD;
    float d = 0.f;
    for(int k = 0; k < HD; k += 8){
      int4 rawv = *(const int4*)(tr + k);
      const bf16* e = (const bf16*)&rawv;
      #pragma unroll
      for(int u = 0; u < 8; u++) d += bf2f(e[u]) * saf[k + u];
    }
    sv[c] = d * TINV;
  }
  __syncthreads();
  for(int k = 0; k < KTOP; k++){
    float bvv = -1e30f; int bi = 0x7fffffff;
    #pragma unroll
    for(int j = 0; j < 4; j++){
      const int i = tid + j*256;
      const float x = sv[i];
      if(x > bvv || (x == bvv && i < bi)){ bvv = x; bi = i; }
    }
    #pragma unroll
    for(int o = 1; o < 64; o <<= 1){
      const float ov = __shfl_xor(bvv, o);
      const int   oi = __shfl_xor(bi, o);
      if(ov > bvv || (ov == bvv && oi < bi)){ bvv = ov; bi = oi; }
    }
    if(lane == 0){ rv[w] = bvv; ri[w] = bi; }
    __syncthreads();
    if(tid == 0){
      for(int w2 = 1; w2 < 4; w2++)
        if(rv[w2] > bvv || (rv[w2] == bvv && ri[w2] < bi)){ bvv = rv[w2]; bi = ri[w2]; }
      if(bi < 0 || bi >= NPOOL) bi = 0;   // NaN-safe: never write OOB
      topv[k] = bvv; topi[k] = bi; sv[bi] = -1e30f;
    }
    __syncthreads();
  }
  if(tid < KTOP) wts[tid] = expf(topv[tid] - topv[0]);
  __syncthreads();
  if(tid == 0){
    float t = 0.f;
    for(int k = 0; k < KTOP; k++) t += wts[k];
    sinv = 1.0f / t;
  }
  __syncthreads();
  float part = 0.f;
  #pragma unroll
  for(int j = 0; j < 3; j++){
    const int h = tid + j*256;
    float ph = 0.f;
    for(int k = 0; k < KTOP; k++) ph += wts[k] * teg[(size_t)topi[k] * HD + h];
    ph *= sinv;
    const float d = afraw[(size_t)s * HD + h] - ph;
    part += d * d;
  }
  part = block_sum(part, buf);
  if(tid == 0) protopart[s] = part;
}

// ------- column moments, stage 1 ---------------------------------------------
__global__ __launch_bounds__(768)
void mom1_kernel(const float* __restrict__ afraw, const float* __restrict__ teg,
                 float* __restrict__ partial){
  const int b = blockIdx.x, h = threadIdx.x;
  float sa = 0.f, sa2 = 0.f, st = 0.f, st2 = 0.f;
  for(int r = b * 40; r < b * 40 + 40; r++){
    if(r < SSAMP){
      const float v = afraw[(size_t)r * HD + h];
      sa += v; sa2 += v * v;
    } else {
      const float v = teg[(size_t)(r - SSAMP) * HD + h];
      st += v; st2 += v * v;
    }
  }
  partial[(size_t)(b*4 + 0) * HD + h] = sa;
  partial[(size_t)(b*4 + 1) * HD + h] = sa2;
  partial[(size_t)(b*4 + 2) * HD + h] = st;
  partial[(size_t)(b*4 + 3) * HD + h] = st2;
}

// ------- final scalars (absorbs mom stage 2), f32 out ------------------------
__global__ __launch_bounds__(1024)
void final_kernel(const float* __restrict__ rs, const float* __restrict__ cs,
                  const float* __restrict__ diag,
                  const float* __restrict__ aux, const int naux,
                  const float* __restrict__ protopart,
                  const float* __restrict__ mompart,
                  float* __restrict__ outsc){
  __shared__ float buf[16];
  const int tid = threadIdx.x;
  float s1 = 0.f, s2 = 0.f;
  for(int r = tid; r < NRr; r += 1024){
    const float dg = diag[r];
    s1 += logf(rs[r]) - dg;
    s2 += logf(cs[r]) - dg;
  }
  float c1 = 0.f;
  for(int j = tid; j < naux; j += 1024) c1 += aux[j];
  float pp = 0.f;
  for(int j = tid; j < SSAMP; j += 1024) pp += protopart[j];
  // moment stage 2 (threads 0..767 = one column each)
  float t1p = 0.f, t2p = 0.f;
  if(tid < HD){
    float sa = 0.f, sa2 = 0.f, st = 0.f, st2 = 0.f;
    for(int b = 0; b < 32; b++){
      sa  += mompart[(size_t)(b*4 + 0) * HD + tid];
      sa2 += mompart[(size_t)(b*4 + 1) * HD + tid];
      st  += mompart[(size_t)(b*4 + 2) * HD + tid];
      st2 += mompart[(size_t)(b*4 + 3) * HD + tid];
    }
    const float ma  = sa * (1.0f / SSAMP);
    const float sda = sqrtf(fmaxf(sa2 * (1.0f / SSAMP) - ma * ma, 0.f));
    const float mt  = st * (1.0f / NPOOL);
    const float sdt = sqrtf(fmaxf(st2 * (1.0f / NPOOL) - mt * mt, 0.f));
    const float dmu = ma - mt, dsd = sda - sdt;
    t1p = dmu * dmu; t2p = dsd * dsd;
  }
  s1 = block_sum(s1, buf);
  s2 = block_sum(s2, buf);
  c1 = block_sum(c1, buf);
  pp = block_sum(pp, buf);
  const float t1 = block_sum(t1p, buf);
  const float t2 = block_sum(t2p, buf);
  if(tid == 0){
    const float con  = 0.5f * (s1 + s2) / (float)NRr;
    const float creg = c1 / 6291456.0f;
    const float tdl  = pp / (float)(SSAMP * HD) + 0.1f * ((t1 + t2) / (float)HD);
    outsc[0] = con;
    outsc[1] = tdl;
    outsc[2] = creg;
  }
}

// =================================================================== host ====
extern "C" void kernel_launch(void* const* d_in, const int* in_sizes, int n_in,
                              void* d_out, int out_size, void* d_ws, size_t ws_size,
                              hipStream_t stream){
  (void)in_sizes; (void)n_in; (void)out_size; (void)ws_size;
  const float* latent = (const float*)d_in[0];
  const float* tokemb = (const float*)d_in[1];
  const float* s_g  = (const float*)d_in[2];  const float* s_bln = (const float*)d_in[3];
  const float* s_w1 = (const float*)d_in[4];  const float* s_b1  = (const float*)d_in[5];
  const float* s_w2 = (const float*)d_in[6];  const float* s_b2  = (const float*)d_in[7];
  const float* b_g  = (const float*)d_in[8];  const float* b_bln = (const float*)d_in[9];
  const float* b_w1 = (const float*)d_in[10]; const float* b_b1  = (const float*)d_in[11];
  const float* b_w2 = (const float*)d_in[12]; const float* b_b2  = (const float*)d_in[13];
  const float* c_g  = (const float*)d_in[14]; const float* c_bln = (const float*)d_in[15];
  const float* c_w1 = (const float*)d_in[16]; const float* c_b1  = (const float*)d_in[17];
  const float* c_w2 = (const float*)d_in[18]; const float* c_b2  = (const float*)d_in[19];
  const float* noise_a = (const float*)d_in[20];
  const float* noise_b = (const float*)d_in[21];
  const int*  samp = (const int*)d_in[22];
  const int*  tok  = (const int*)d_in[23];

  float* out = (float*)d_out;
  float* out_aligned = out;                                   // [NRr*HD]
  float* out_scalars = out + (size_t)NRr * HD;                // [3]
  float* out_scale   = out + (size_t)NRr * HD + 3;            // [NRr*HD]
  float* out_bias    = out_scale + (size_t)NRr * HD;          // [NRr*HD]

  char* wp = (char*)d_ws;
  auto alloc = [&](size_t bytes) -> char* {
    char* p = wp; wp += (bytes + 255) & ~(size_t)255; return p;
  };
  bf16* wt_comb1 = (bf16*)alloc((size_t)2*HD*HD*2);
  bf16* wt_c1    = (bf16*)alloc((size_t)HD*HD*2);
  bf16* wt_s2    = (bf16*)alloc((size_t)HD*HD*2);
  bf16* wt_b2    = (bf16*)alloc((size_t)HD*HD*2);
  bf16* wt_c2    = (bf16*)alloc((size_t)HD*HD*2);
  float* bcomb1  = (float*)alloc(2*HD*4);
  float* bc1     = (float*)alloc(HD*4);
  bf16* A1 = (bf16*)alloc((size_t)2*NRr*HD*2);
  bf16* A2 = (bf16*)alloc((size_t)2*NRr*HD*2);
  float* rowpart = (float*)alloc((size_t)64*NRr*4);
  float* colpart = (float*)alloc((size_t)64*NRr*4);
  float* rowsum  = (float*)alloc((size_t)NRr*4);
  float* colsum  = (float*)alloc((size_t)NRr*4);
  float* diag    = (float*)alloc((size_t)NRr*4);
  float* aux     = (float*)alloc(768*4);
  float* afraw   = (float*)alloc((size_t)SSAMP*HD*4);
  float* teg     = (float*)alloc((size_t)NPOOL*HD*4);
  float* protopart = (float*)alloc(SSAMP*4);
  // phase-disjoint aliases (rowpart/colpart dead after rcsum)
  float* mompart = rowpart;
  bf16*  ten     = (bf16*)colpart;
  bf16*  afn     = (bf16*)(colpart + ((size_t)NPOOL*HD*2)/4);

  // weight prep: 6 transposes in one launch; 3 folded biases in one launch
  TsA ts;
  ts.w[0]=s_w1; ts.gg[0]=s_g;     ts.o[0]=wt_comb1;
  ts.w[1]=b_w1; ts.gg[1]=b_g;     ts.o[1]=wt_comb1 + (size_t)HD*HD;
  ts.w[2]=c_w1; ts.gg[2]=c_g;     ts.o[2]=wt_c1;
  ts.w[3]=s_w2; ts.gg[3]=nullptr; ts.o[3]=wt_s2;
  ts.w[4]=b_w2; ts.gg[4]=nullptr; ts.o[4]=wt_b2;
  ts.w[5]=c_w2; ts.gg[5]=nullptr; ts.o[5]=wt_c2;
  tscale6<<<dim3(24,24,6), dim3(32,8), 0, stream>>>(ts);
  FbA fb;
  fb.bln[0]=s_bln; fb.w1[0]=s_w1; fb.b1[0]=s_b1; fb.o[0]=bcomb1;
  fb.bln[1]=b_bln; fb.w1[1]=b_w1; fb.b1[1]=b_b1; fb.o[1]=bcomb1 + HD;
  fb.bln[2]=c_bln; fb.w1[2]=c_w1; fb.b1[2]=c_b1; fb.o[2]=bc1;
  foldbias3<<<dim3(12,3), 256, 0, stream>>>(fb);

  // scale+bias heads
  lnxh_kernel<<<NRr, 256, 0, stream>>>(latent, A2);
  gemm_kernel<EPI_GELU><<<dim3(12,64), 256, 0, stream>>>(
      A2, wt_comb1, nullptr, NRr, 2*HD, HD, HD, 2*HD, bcomb1, nullptr,
      A1, nullptr, nullptr, nullptr, nullptr);
  gemm_kernel<EPI_SB><<<dim3(6,64,2), 256, 0, stream>>>(
      A1, wt_s2, wt_b2, NRr, HD, HD, 2*HD, HD, s_b2, b_b2,
      nullptr, out_scale, out_bias, aux, nullptr);

  // fused aligned + both noisy LNs
  fuse_al_ln<<<NRr, 256, 0, stream>>>(latent, out_scale, out_bias,
                                      noise_a, noise_b, out_aligned, A1);

  // contrastive heads a|b stacked
  gemm_kernel<EPI_GELU><<<dim3(6,128), 256, 0, stream>>>(
      A1, wt_c1, nullptr, 2*NRr, HD, HD, HD, HD, bc1, nullptr,
      A2, nullptr, nullptr, nullptr, nullptr);
  gemm_kernel<EPI_RAW><<<dim3(6,128), 256, 0, stream>>>(
      A2, wt_c2, nullptr, 2*NRr, HD, HD, HD, HD, c_b2, nullptr,
      A1, nullptr, nullptr, nullptr, nullptr);
  // fused in-place l2norm of va|vb + diag
  l2ndiag_kernel<<<NRr, 256, 0, stream>>>(A1, diag);
  bf16* va = A1;
  bf16* vb = A1 + (size_t)NRr * HD;

  // streaming logits LSE (proven 128^2 2-phase, BK=64, swizzled)
  gemm_kernel<EPI_LOGITS><<<dim3(64,64), 256, 0, stream>>>(
      va, vb, nullptr, NRr, NRr, HD, HD, 0, nullptr, nullptr,
      nullptr, nullptr, nullptr, rowpart, colpart);
  rcsum_kernel<<<NRr / 256, 256, 0, stream>>>(rowpart, colpart, rowsum, colsum, 64);

  // token distribution path
  gather_kernel<<<SSAMP + NPOOL, 256, 0, stream>>>(out_aligned, samp, afraw, afn,
                                                   tokemb, tok, teg, ten);
  topk_kernel<<<SSAMP, 256, 0, stream>>>(afn, ten, teg, afraw, protopart);
  mom1_kernel<<<32, 768, 0, stream>>>(afraw, teg, mompart);

  final_kernel<<<1, 1024, 0, stream>>>(rowsum, colsum, diag, aux, 768,
                                       protopart, mompart, out_scalars);
}

// Round 11
// 481.241 us; speedup vs baseline: 1.0775x; 1.0775x over previous
//
#include <hip/hip_runtime.h>
#include <hip/hip_bf16.h>

typedef __hip_bfloat16 bf16;
typedef __attribute__((ext_vector_type(4))) float f32x4;
typedef __attribute__((ext_vector_type(8))) short bf16x8v;

static constexpr int   HD    = 768;
static constexpr int   NRr   = 8192;     // B*T
static constexpr int   SSAMP = 256;
static constexpr int   KTOP  = 64;
static constexpr int   NPOOL = 1024;
static constexpr float TINV  = 10.0f;    // 1/TEMP

__device__ __forceinline__ float bf2f(bf16 h){ return __bfloat162float(h); }
__device__ __forceinline__ bf16  f2bf(float f){ return __float2bfloat16(f); }

__device__ __forceinline__ float gelu_exact(float x){
  return 0.5f * x * (1.0f + erff(x * 0.70710678118654752f));
}

// deterministic block sum; buf must hold blockDim.x/64 floats
__device__ __forceinline__ float block_sum(float v, float* buf){
  const int lane = threadIdx.x & 63, w = threadIdx.x >> 6;
  const int nw = (int)blockDim.x >> 6;
  #pragma unroll
  for(int o = 32; o; o >>= 1) v += __shfl_down(v, o);
  __syncthreads();
  if(lane == 0) buf[w] = v;
  __syncthreads();
  float t = 0.f;
  for(int i = 0; i < nw; i++) t += buf[i];
  return t;
}

// dual block sum (256 threads); buf must hold 8 floats
__device__ __forceinline__ void block_sum2(float& a, float& b, float* buf){
  const int lane = threadIdx.x & 63, w = threadIdx.x >> 6;
  #pragma unroll
  for(int o = 32; o; o >>= 1){ a += __shfl_down(a, o); b += __shfl_down(b, o); }
  __syncthreads();
  if(lane == 0){ buf[w] = a; buf[4 + w] = b; }
  __syncthreads();
  float ta = 0.f, tb = 0.f;
  #pragma unroll
  for(int i = 0; i < 4; i++){ ta += buf[i]; tb += buf[4 + i]; }
  a = ta; b = tb;
}

__device__ __forceinline__ void gload_lds16(const bf16* g, bf16* lds_uniform){
  __builtin_amdgcn_global_load_lds(
      (const __attribute__((address_space(1))) unsigned int*)(const void*)g,
      (__attribute__((address_space(3))) unsigned int*)(void*)lds_uniform,
      16, 0, 0);
}

// ---- fused 6x transpose 768x768 with optional gain fold ---------------------
struct TsA { const float* w[6]; const float* gg[6]; bf16* o[6]; };
__global__ __launch_bounds__(256)
void tscale6(TsA a){
  __shared__ float t[32][33];
  const int z = blockIdx.z;
  const float* Win = a.w[z];
  const float* g   = a.gg[z];
  bf16* Wt         = a.o[z];
  const int tx = threadIdx.x, ty = threadIdx.y;     // (32,8)
  const int bx = blockIdx.x * 32, by = blockIdx.y * 32;
  #pragma unroll
  for(int j = 0; j < 4; j++)
    t[ty + j*8][tx] = Win[(size_t)(by + ty + j*8) * HD + bx + tx];
  __syncthreads();
  const float gv = g ? g[by + tx] : 1.0f;
  #pragma unroll
  for(int j = 0; j < 4; j++)
    Wt[(size_t)(bx + ty + j*8) * HD + by + tx] = f2bf(gv * t[tx][ty + j*8]);
}

// ---- fused folded-bias: o[h][n] = b1[h][n] + sum_k bln[h][k]*w1[h][k][n] ----
struct FbA { const float* bln[3]; const float* w1[3]; const float* b1[3]; float* o[3]; };
__global__ __launch_bounds__(256)
void foldbias3(FbA a){
  __shared__ float red[4][64];
  const int h = blockIdx.y;
  const int lane = threadIdx.x & 63, w = threadIdx.x >> 6;
  const int n = blockIdx.x * 64 + lane;
  const float* bl = a.bln[h];
  const float* w1 = a.w1[h];
  float t = 0.f;
  for(int k = w * 192; k < w * 192 + 192; k++)
    t += bl[k] * w1[(size_t)k * HD + n];
  red[w][lane] = t;
  __syncthreads();
  if(w == 0)
    a.o[h][n] = a.b1[h][n] + red[0][lane] + red[1][lane] + red[2][lane] + red[3][lane];
}

// ---- LayerNorm core xh=(x-m)/sigma (affine folded into weights), f32->bf16 --
__global__ __launch_bounds__(256)
void lnxh_kernel(const float* __restrict__ x, bf16* __restrict__ o){
  __shared__ float buf[4];
  const int row = blockIdx.x, tid = threadIdx.x;
  const size_t base = (size_t)row * HD;
  float v[3];
  #pragma unroll
  for(int j = 0; j < 3; j++) v[j] = x[base + tid + j*256];
  float s = v[0] + v[1] + v[2];
  s = block_sum(s, buf);
  const float m = s * (1.0f / HD);
  float q = 0.f;
  #pragma unroll
  for(int j = 0; j < 3; j++){ const float d = v[j] - m; q += d*d; }
  q = block_sum(q, buf);
  const float inv = rsqrtf(q * (1.0f / HD) + 1e-5f);
  #pragma unroll
  for(int j = 0; j < 3; j++)
    o[base + tid + j*256] = f2bf((v[j] - m) * inv);
}

// ---- fused: aligned = sc*latent+bi (write f32) + dual noisy LN -> X (bf16) --
__global__ __launch_bounds__(256)
void fuse_al_ln(const float* __restrict__ latent, const float* __restrict__ sc,
                const float* __restrict__ bi, const float* __restrict__ na,
                const float* __restrict__ nb, float* __restrict__ out_aligned,
                bf16* __restrict__ X){
  __shared__ float buf[8];
  const int row = blockIdx.x, tid = threadIdx.x;
  const size_t base = (size_t)row * HD;
  float ua[3], ub[3];
  #pragma unroll
  for(int j = 0; j < 3; j++){
    const int i = tid + j*256;
    const float a = sc[base + i] * latent[base + i] + bi[base + i];
    out_aligned[base + i] = a;
    ua[j] = a + na[base + i];
    ub[j] = a + nb[base + i];
  }
  float sa = ua[0] + ua[1] + ua[2];
  float sb = ub[0] + ub[1] + ub[2];
  block_sum2(sa, sb, buf);
  const float ma = sa * (1.0f / HD), mb = sb * (1.0f / HD);
  float qa = 0.f, qb = 0.f;
  #pragma unroll
  for(int j = 0; j < 3; j++){
    const float da = ua[j] - ma; qa += da*da;
    const float db = ub[j] - mb; qb += db*db;
  }
  block_sum2(qa, qb, buf);
  const float ia = rsqrtf(qa * (1.0f / HD) + 1e-5f);
  const float ib = rsqrtf(qb * (1.0f / HD) + 1e-5f);
  #pragma unroll
  for(int j = 0; j < 3; j++){
    const int i = tid + j*256;
    X[base + i] = f2bf((ua[j] - ma) * ia);
    X[(size_t)(row + NRr) * HD + i] = f2bf((ub[j] - mb) * ib);
  }
}

// ---------------- GEMM: C[M,N] = A[M,K] * Bt[N,K]^T, BK=64, fused epilogues --
// LDS granule swizzle (8 granules/row): phys p of row r holds global granule
// g=(p-(r&7))&7; reader of logical granule gl uses p=((gl)+(r16&7))&7.
enum { EPI_GELU = 0, EPI_SB = 1, EPI_RAW = 3, EPI_LOGITS = 4 };

template<int EPI>
__global__ __launch_bounds__(256, 2)
void gemm_kernel(const bf16* __restrict__ A, const bf16* __restrict__ Bt,
                 const bf16* __restrict__ Bt2,
                 const int M, const int N, const int K,
                 const int lda, const int ldc,
                 const float* __restrict__ bias, const float* __restrict__ bias2,
                 bf16* __restrict__ outb, float* __restrict__ outf,
                 float* __restrict__ outf2,
                 float* __restrict__ aux, float* __restrict__ aux2){
  __shared__ __align__(16) bf16 As[128 * 64];
  __shared__ __align__(16) bf16 Bs[128 * 64];
  __shared__ float rbuf[512];

  const int tid  = threadIdx.x;
  const int wave = tid >> 6, lane = tid & 63;
  const int wm = wave >> 1, wn = wave & 1;
  const int r16 = lane & 15, kh = lane >> 4;
  const int bx = blockIdx.x, by = blockIdx.y;
  const int row0 = by * 128, col0 = bx * 128;

  float addv = 0.f;
  if constexpr(EPI == EPI_SB){
    if(blockIdx.z == 0){ addv = 1.0f; }
    else { A += 768; Bt = Bt2; bias = bias2; outf = outf2; }
  }

  f32x4 acc[4][4];
  #pragma unroll
  for(int i = 0; i < 4; i++)
    #pragma unroll
    for(int j = 0; j < 4; j++){ f32x4 z = {0.f,0.f,0.f,0.f}; acc[i][j] = z; }

  // staging: tile 128x64 bf16 = 1024 chunks of 16B; chunk c: row=c>>3, p=c&7
  const bf16* gA[4]; const bf16* gB[4];
  bf16* lA[4]; bf16* lB[4];
  #pragma unroll
  for(int j = 0; j < 4; j++){
    const int c = tid + j*256;
    const int rr = c >> 3, p = c & 7;
    const int g = (p - (rr & 7)) & 7;           // pre-swizzled global granule
    gA[j] = A  + (size_t)(row0 + rr) * lda + g * 8;
    gB[j] = Bt + (size_t)(col0 + rr) * K   + g * 8;
    lA[j] = As + ((size_t)j*256 + wave*64) * 8; // wave-uniform LDS bases (linear)
    lB[j] = Bs + ((size_t)j*256 + wave*64) * 8;
  }
  const int sw = r16 & 7;

  for(int k0 = 0; k0 < K; k0 += 64){
    __syncthreads();
    #pragma unroll
    for(int j = 0; j < 4; j++){
      gload_lds16(gA[j] + k0, lA[j]);
      gload_lds16(gB[j] + k0, lB[j]);
    }
    __syncthreads();
    #pragma unroll
    for(int kk = 0; kk < 2; kk++){
      const int koff = ((kk*4 + kh + sw) & 7) * 8;
      bf16x8v av[4], bv[4];
      #pragma unroll
      for(int f = 0; f < 4; f++){
        av[f] = *(const bf16x8v*)(As + (wm*64 + f*16 + r16) * 64 + koff);
        bv[f] = *(const bf16x8v*)(Bs + (wn*64 + f*16 + r16) * 64 + koff);
      }
      #pragma unroll
      for(int i = 0; i < 4; i++)
        #pragma unroll
        for(int j = 0; j < 4; j++)
          acc[i][j] = __builtin_amdgcn_mfma_f32_16x16x32_bf16(av[i], bv[j], acc[i][j], 0, 0, 0);
    }
  }

  const int crow0 = row0 + wm * 64;
  const int ccol0 = col0 + wn * 64;

  if constexpr(EPI != EPI_LOGITS){
    float part = 0.f;
    #pragma unroll
    for(int i = 0; i < 4; i++){
      #pragma unroll
      for(int j = 0; j < 4; j++){
        const int col = ccol0 + j*16 + r16;
        const float bvv = bias ? bias[col] : 0.f;
        #pragma unroll
        for(int q = 0; q < 4; q++){
          const int row = crow0 + i*16 + kh*4 + q;
          const float v = acc[i][j][q] + bvv;
          const size_t off = (size_t)row * ldc + col;
          if constexpr(EPI == EPI_GELU){
            outb[off] = f2bf(gelu_exact(v));
          } else if constexpr(EPI == EPI_SB){
            const float t = 0.25f * tanhf(v);
            outf[off] = t + addv;
            part += t * t;
          } else {                      // EPI_RAW: bf16 out, l2norm later
            outb[off] = f2bf(v);
          }
        }
      }
    }
    if constexpr(EPI == EPI_SB){
      const float tot2 = block_sum(part, rbuf);
      if(tid == 0)
        aux[(size_t)blockIdx.z * (gridDim.x * gridDim.y) + by * gridDim.x + bx] = tot2;
    }
  } else {
    // logits tile: e = exp(10*acc); deterministic row/col partial sums
    float rs[16], cs[4];
    #pragma unroll
    for(int t = 0; t < 16; t++) rs[t] = 0.f;
    #pragma unroll
    for(int t = 0; t < 4; t++) cs[t] = 0.f;
    #pragma unroll
    for(int i = 0; i < 4; i++)
      #pragma unroll
      for(int j = 0; j < 4; j++)
        #pragma unroll
        for(int q = 0; q < 4; q++){
          const float ev = expf(acc[i][j][q] * TINV);
          rs[i*4 + q] += ev;
          cs[j]       += ev;
        }
    #pragma unroll
    for(int t = 0; t < 16; t++){
      float r = rs[t];
      r += __shfl_xor(r, 1); r += __shfl_xor(r, 2);
      r += __shfl_xor(r, 4); r += __shfl_xor(r, 8);
      rs[t] = r;
    }
    if(r16 == 0){
      #pragma unroll
      for(int i = 0; i < 4; i++)
        #pragma unroll
        for(int q = 0; q < 4; q++)
          rbuf[wn*128 + wm*64 + i*16 + kh*4 + q] = rs[i*4 + q];
    }
    #pragma unroll
    for(int j = 0; j < 4; j++){
      float c = cs[j];
      c += __shfl_xor(c, 16); c += __shfl_xor(c, 32);
      cs[j] = c;
    }
    if(kh == 0){
      #pragma unroll
      for(int j = 0; j < 4; j++)
        rbuf[256 + wm*128 + wn*64 + j*16 + r16] = cs[j];
    }
    __syncthreads();
    if(tid < 128){
      aux [(size_t)bx * M + row0 + tid] = rbuf[tid]       + rbuf[128 + tid];
      aux2[(size_t)by * M + col0 + tid] = rbuf[256 + tid] + rbuf[384 + tid];
    }
  }
}

// ---- fused: in-place l2-normalize va & vb row + diag = 10*dot(van, vbn) -----
__global__ __launch_bounds__(256)
void l2ndiag_kernel(bf16* __restrict__ vab, float* __restrict__ diag){
  __shared__ float buf[8];
  const int row = blockIdx.x, tid = threadIdx.x;
  const size_t basea = (size_t)row * HD;
  const size_t baseb = basea + (size_t)NRr * HD;
  float a[3], b[3];
  #pragma unroll
  for(int j = 0; j < 3; j++){
    a[j] = bf2f(vab[basea + tid + j*256]);
    b[j] = bf2f(vab[baseb + tid + j*256]);
  }
  float qa = a[0]*a[0] + a[1]*a[1] + a[2]*a[2];
  float qb = b[0]*b[0] + b[1]*b[1] + b[2]*b[2];
  block_sum2(qa, qb, buf);
  const float ia = 1.0f / fmaxf(sqrtf(qa), 1e-12f);
  const float ib = 1.0f / fmaxf(sqrtf(qb), 1e-12f);
  float d = 0.f;
  #pragma unroll
  for(int j = 0; j < 3; j++){
    const bf16 oa = f2bf(a[j] * ia);
    const bf16 ob = f2bf(b[j] * ib);
    vab[basea + tid + j*256] = oa;
    vab[baseb + tid + j*256] = ob;
    d += bf2f(oa) * bf2f(ob);
  }
  d = block_sum(d, buf);
  if(tid == 0) diag[row] = d * TINV;
}

// ---------------- sum partials per row/col -----------------------------------
__global__ __launch_bounds__(256)
void rcsum_kernel(const float* __restrict__ rp, const float* __restrict__ cp,
                  float* __restrict__ rs, float* __restrict__ cs, const int nb){
  const int i = blockIdx.x * 256 + threadIdx.x;
  float r = 0.f, c = 0.f;
  for(int b = 0; b < nb; b++){
    r += rp[(size_t)b * NRr + i];
    c += cp[(size_t)b * NRr + i];
  }
  rs[i] = r; cs[i] = c;
}

// ------- fused gather: af rows (blocks 0..255) + te rows (256..1279) ---------
__global__ __launch_bounds__(256)
void gather_kernel(const float* __restrict__ aligned, const int* __restrict__ samp,
                   float* __restrict__ afraw, bf16* __restrict__ afn,
                   const float* __restrict__ emb, const int* __restrict__ tok,
                   float* __restrict__ teg, bf16* __restrict__ ten){
  __shared__ float buf[4];
  const int tid = threadIdx.x;
  if(blockIdx.x < SSAMP){
    const int s = blockIdx.x;
    const size_t src = (size_t)samp[s] * HD, dst = (size_t)s * HD;
    float v[3];
    #pragma unroll
    for(int j = 0; j < 3; j++){
      const int i = tid + j*256;
      v[j] = aligned[src + i];
      afraw[dst + i] = v[j];
    }
    float q = v[0]*v[0] + v[1]*v[1] + v[2]*v[2];
    q = block_sum(q, buf);
    const float inv = 1.0f / fmaxf(sqrtf(q), 1e-12f);
    #pragma unroll
    for(int j = 0; j < 3; j++) afn[dst + tid + j*256] = f2bf(v[j] * inv);
  } else {
    const int p = blockIdx.x - SSAMP;
    const size_t src = (size_t)tok[p] * HD, dst = (size_t)p * HD;
    float v[3];
    #pragma unroll
    for(int j = 0; j < 3; j++){
      const int i = tid + j*256;
      v[j] = emb[src + i];
      teg[dst + i] = v[j];
    }
    float q = v[0]*v[0] + v[1]*v[1] + v[2]*v[2];
    q = block_sum(q, buf);
    const float inv = 1.0f / fmaxf(sqrtf(q), 1e-12f);
    #pragma unroll
    for(int j = 0; j < 3; j++) ten[dst + tid + j*256] = f2bf(v[j] * inv);
  }
}

// ---- per-row: sims -> bitonic top-64 -> softmax -> proto -> sq-err ----------
// Selection: full 1024-elem bitonic sort (desc by value, asc by index on ties)
// — matches jax.lax.top_k's stable ordering; top-64 = slots 0..63.
__global__ __launch_bounds__(256)
void topk_kernel(const bf16* __restrict__ afn, const bf16* __restrict__ ten,
                 const float* __restrict__ teg, const float* __restrict__ afraw,
                 float* __restrict__ protopart){
  __shared__ float saf[HD];
  __shared__ float sv[NPOOL];
  __shared__ int   si[NPOOL];
  __shared__ float wts[KTOP];
  __shared__ float buf[4];
  __shared__ float sinv;
  const int s = blockIdx.x, tid = threadIdx.x;
  // load normalized af row into LDS (f32)
  #pragma unroll
  for(int j = 0; j < 3; j++) saf[tid + j*256] = bf2f(afn[(size_t)s * HD + tid + j*256]);
  __syncthreads();
  // inline tl: sv[c] = 10 * dot(afn[s], ten[c])
  #pragma unroll
  for(int cb = 0; cb < 4; cb++){
    const int c = tid + cb * 256;
    const bf16* tr = ten + (size_t)c * HD;
    float d = 0.f;
    for(int k = 0; k < HD; k += 8){
      int4 rawv = *(const int4*)(tr + k);
      const bf16* e = (const bf16*)&rawv;
      #pragma unroll
      for(int u = 0; u < 8; u++) d += bf2f(e[u]) * saf[k + u];
    }
    sv[c] = d * TINV;
    si[c] = c;
  }
  // bitonic sort, descending (value desc, index asc)
  for(int k2 = 2; k2 <= NPOOL; k2 <<= 1){
    for(int j = k2 >> 1; j > 0; j >>= 1){
      __syncthreads();
      #pragma unroll
      for(int q = 0; q < 4; q++){
        const int i = tid + q * 256;
        const int ixj = i ^ j;
        if(ixj > i){
          const float v1 = sv[i],  v2 = sv[ixj];
          const int   i1 = si[i],  i2 = si[ixj];
          // g: arr[i] should precede arr[ixj] in final descending order
          const bool g = (v1 > v2) || (v1 == v2 && i1 < i2);
          const bool swap = ((i & k2) == 0) ? !g : g;
          if(swap){ sv[i] = v2; sv[ixj] = v1; si[i] = i2; si[ixj] = i1; }
        }
      }
    }
  }
  __syncthreads();
  if(tid < KTOP) wts[tid] = expf(sv[tid] - sv[0]);
  __syncthreads();
  if(tid == 0){
    float t = 0.f;
    for(int k = 0; k < KTOP; k++) t += wts[k];
    sinv = 1.0f / t;
  }
  __syncthreads();
  float part = 0.f;
  #pragma unroll
  for(int j = 0; j < 3; j++){
    const int h = tid + j*256;
    float ph = 0.f;
    for(int k = 0; k < KTOP; k++) ph += wts[k] * teg[(size_t)si[k] * HD + h];
    ph *= sinv;
    const float d = afraw[(size_t)s * HD + h] - ph;
    part += d * d;
  }
  part = block_sum(part, buf);
  if(tid == 0) protopart[s] = part;
}

// ------- column moments, stage 1 ---------------------------------------------
__global__ __launch_bounds__(768)
void mom1_kernel(const float* __restrict__ afraw, const float* __restrict__ teg,
                 float* __restrict__ partial){
  const int b = blockIdx.x, h = threadIdx.x;
  float sa = 0.f, sa2 = 0.f, st = 0.f, st2 = 0.f;
  for(int r = b * 40; r < b * 40 + 40; r++){
    if(r < SSAMP){
      const float v = afraw[(size_t)r * HD + h];
      sa += v; sa2 += v * v;
    } else {
      const float v = teg[(size_t)(r - SSAMP) * HD + h];
      st += v; st2 += v * v;
    }
  }
  partial[(size_t)(b*4 + 0) * HD + h] = sa;
  partial[(size_t)(b*4 + 1) * HD + h] = sa2;
  partial[(size_t)(b*4 + 2) * HD + h] = st;
  partial[(size_t)(b*4 + 3) * HD + h] = st2;
}

// ------- final scalars (absorbs mom stage 2), f32 out ------------------------
__global__ __launch_bounds__(1024)
void final_kernel(const float* __restrict__ rs, const float* __restrict__ cs,
                  const float* __restrict__ diag,
                  const float* __restrict__ aux, const int naux,
                  const float* __restrict__ protopart,
                  const float* __restrict__ mompart,
                  float* __restrict__ outsc){
  __shared__ float buf[16];
  const int tid = threadIdx.x;
  float s1 = 0.f, s2 = 0.f;
  for(int r = tid; r < NRr; r += 1024){
    const float dg = diag[r];
    s1 += logf(rs[r]) - dg;
    s2 += logf(cs[r]) - dg;
  }
  float c1 = 0.f;
  for(int j = tid; j < naux; j += 1024) c1 += aux[j];
  float pp = 0.f;
  for(int j = tid; j < SSAMP; j += 1024) pp += protopart[j];
  // moment stage 2 (threads 0..767 = one column each)
  float t1p = 0.f, t2p = 0.f;
  if(tid < HD){
    float sa = 0.f, sa2 = 0.f, st = 0.f, st2 = 0.f;
    for(int b = 0; b < 32; b++){
      sa  += mompart[(size_t)(b*4 + 0) * HD + tid];
      sa2 += mompart[(size_t)(b*4 + 1) * HD + tid];
      st  += mompart[(size_t)(b*4 + 2) * HD + tid];
      st2 += mompart[(size_t)(b*4 + 3) * HD + tid];
    }
    const float ma  = sa * (1.0f / SSAMP);
    const float sda = sqrtf(fmaxf(sa2 * (1.0f / SSAMP) - ma * ma, 0.f));
    const float mt  = st * (1.0f / NPOOL);
    const float sdt = sqrtf(fmaxf(st2 * (1.0f / NPOOL) - mt * mt, 0.f));
    const float dmu = ma - mt, dsd = sda - sdt;
    t1p = dmu * dmu; t2p = dsd * dsd;
  }
  s1 = block_sum(s1, buf);
  s2 = block_sum(s2, buf);
  c1 = block_sum(c1, buf);
  pp = block_sum(pp, buf);
  const float t1 = block_sum(t1p, buf);
  const float t2 = block_sum(t2p, buf);
  if(tid == 0){
    const float con  = 0.5f * (s1 + s2) / (float)NRr;
    const float creg = c1 / 6291456.0f;
    const float tdl  = pp / (float)(SSAMP * HD) + 0.1f * ((t1 + t2) / (float)HD);
    outsc[0] = con;
    outsc[1] = tdl;
    outsc[2] = creg;
  }
}

// =================================================================== host ====
extern "C" void kernel_launch(void* const* d_in, const int* in_sizes, int n_in,
                              void* d_out, int out_size, void* d_ws, size_t ws_size,
                              hipStream_t stream){
  (void)in_sizes; (void)n_in; (void)out_size; (void)ws_size;
  const float* latent = (const float*)d_in[0];
  const float* tokemb = (const float*)d_in[1];
  const float* s_g  = (const float*)d_in[2];  const float* s_bln = (const float*)d_in[3];
  const float* s_w1 = (const float*)d_in[4];  const float* s_b1  = (const float*)d_in[5];
  const float* s_w2 = (const float*)d_in[6];  const float* s_b2  = (const float*)d_in[7];
  const float* b_g  = (const float*)d_in[8];  const float* b_bln = (const float*)d_in[9];
  const float* b_w1 = (const float*)d_in[10]; const float* b_b1  = (const float*)d_in[11];
  const float* b_w2 = (const float*)d_in[12]; const float* b_b2  = (const float*)d_in[13];
  const float* c_g  = (const float*)d_in[14]; const float* c_bln = (const float*)d_in[15];
  const float* c_w1 = (const float*)d_in[16]; const float* c_b1  = (const float*)d_in[17];
  const float* c_w2 = (const float*)d_in[18]; const float* c_b2  = (const float*)d_in[19];
  const float* noise_a = (const float*)d_in[20];
  const float* noise_b = (const float*)d_in[21];
  const int*  samp = (const int*)d_in[22];
  const int*  tok  = (const int*)d_in[23];

  float* out = (float*)d_out;
  float* out_aligned = out;                                   // [NRr*HD]
  float* out_scalars = out + (size_t)NRr * HD;                // [3]
  float* out_scale   = out + (size_t)NRr * HD + 3;            // [NRr*HD]
  float* out_bias    = out_scale + (size_t)NRr * HD;          // [NRr*HD]

  char* wp = (char*)d_ws;
  auto alloc = [&](size_t bytes) -> char* {
    char* p = wp; wp += (bytes + 255) & ~(size_t)255; return p;
  };
  bf16* wt_comb1 = (bf16*)alloc((size_t)2*HD*HD*2);
  bf16* wt_c1    = (bf16*)alloc((size_t)HD*HD*2);
  bf16* wt_s2    = (bf16*)alloc((size_t)HD*HD*2);
  bf16* wt_b2    = (bf16*)alloc((size_t)HD*HD*2);
  bf16* wt_c2    = (bf16*)alloc((size_t)HD*HD*2);
  float* bcomb1  = (float*)alloc(2*HD*4);
  float* bc1     = (float*)alloc(HD*4);
  bf16* A1 = (bf16*)alloc((size_t)2*NRr*HD*2);
  bf16* A2 = (bf16*)alloc((size_t)2*NRr*HD*2);
  float* rowpart = (float*)alloc((size_t)64*NRr*4);
  float* colpart = (float*)alloc((size_t)64*NRr*4);
  float* rowsum  = (float*)alloc((size_t)NRr*4);
  float* colsum  = (float*)alloc((size_t)NRr*4);
  float* diag    = (float*)alloc((size_t)NRr*4);
  float* aux     = (float*)alloc(768*4);
  float* afraw   = (float*)alloc((size_t)SSAMP*HD*4);
  float* teg     = (float*)alloc((size_t)NPOOL*HD*4);
  float* protopart = (float*)alloc(SSAMP*4);
  // phase-disjoint aliases (rowpart/colpart dead after rcsum)
  float* mompart = rowpart;
  bf16*  ten     = (bf16*)colpart;
  bf16*  afn     = (bf16*)(colpart + ((size_t)NPOOL*HD*2)/4);

  // weight prep: 6 transposes in one launch; 3 folded biases in one launch
  TsA ts;
  ts.w[0]=s_w1; ts.gg[0]=s_g;     ts.o[0]=wt_comb1;
  ts.w[1]=b_w1; ts.gg[1]=b_g;     ts.o[1]=wt_comb1 + (size_t)HD*HD;
  ts.w[2]=c_w1; ts.gg[2]=c_g;     ts.o[2]=wt_c1;
  ts.w[3]=s_w2; ts.gg[3]=nullptr; ts.o[3]=wt_s2;
  ts.w[4]=b_w2; ts.gg[4]=nullptr; ts.o[4]=wt_b2;
  ts.w[5]=c_w2; ts.gg[5]=nullptr; ts.o[5]=wt_c2;
  tscale6<<<dim3(24,24,6), dim3(32,8), 0, stream>>>(ts);
  FbA fb;
  fb.bln[0]=s_bln; fb.w1[0]=s_w1; fb.b1[0]=s_b1; fb.o[0]=bcomb1;
  fb.bln[1]=b_bln; fb.w1[1]=b_w1; fb.b1[1]=b_b1; fb.o[1]=bcomb1 + HD;
  fb.bln[2]=c_bln; fb.w1[2]=c_w1; fb.b1[2]=c_b1; fb.o[2]=bc1;
  foldbias3<<<dim3(12,3), 256, 0, stream>>>(fb);

  // scale+bias heads
  lnxh_kernel<<<NRr, 256, 0, stream>>>(latent, A2);
  gemm_kernel<EPI_GELU><<<dim3(12,64), 256, 0, stream>>>(
      A2, wt_comb1, nullptr, NRr, 2*HD, HD, HD, 2*HD, bcomb1, nullptr,
      A1, nullptr, nullptr, nullptr, nullptr);
  gemm_kernel<EPI_SB><<<dim3(6,64,2), 256, 0, stream>>>(
      A1, wt_s2, wt_b2, NRr, HD, HD, 2*HD, HD, s_b2, b_b2,
      nullptr, out_scale, out_bias, aux, nullptr);

  // fused aligned + both noisy LNs
  fuse_al_ln<<<NRr, 256, 0, stream>>>(latent, out_scale, out_bias,
                                      noise_a, noise_b, out_aligned, A1);

  // contrastive heads a|b stacked
  gemm_kernel<EPI_GELU><<<dim3(6,128), 256, 0, stream>>>(
      A1, wt_c1, nullptr, 2*NRr, HD, HD, HD, HD, bc1, nullptr,
      A2, nullptr, nullptr, nullptr, nullptr);
  gemm_kernel<EPI_RAW><<<dim3(6,128), 256, 0, stream>>>(
      A2, wt_c2, nullptr, 2*NRr, HD, HD, HD, HD, c_b2, nullptr,
      A1, nullptr, nullptr, nullptr, nullptr);
  // fused in-place l2norm of va|vb + diag
  l2ndiag_kernel<<<NRr, 256, 0, stream>>>(A1, diag);
  bf16* va = A1;
  bf16* vb = A1 + (size_t)NRr * HD;

  // streaming logits LSE (proven 128^2 2-phase, BK=64, swizzled)
  gemm_kernel<EPI_LOGITS><<<dim3(64,64), 256, 0, stream>>>(
      va, vb, nullptr, NRr, NRr, HD, HD, 0, nullptr, nullptr,
      nullptr, nullptr, nullptr, rowpart, colpart);
  rcsum_kernel<<<NRr / 256, 256, 0, stream>>>(rowpart, colpart, rowsum, colsum, 64);

  // token distribution path
  gather_kernel<<<SSAMP + NPOOL, 256, 0, stream>>>(out_aligned, samp, afraw, afn,
                                                   tokemb, tok, teg, ten);
  topk_kernel<<<SSAMP, 256, 0, stream>>>(afn, ten, teg, afraw, protopart);
  mom1_kernel<<<32, 768, 0, stream>>>(afraw, teg, mompart);

  final_kernel<<<1, 1024, 0, stream>>>(rowsum, colsum, diag, aux, 768,
                                       protopart, mompart, out_scalars);
}